// Round 2
// baseline (1653.261 us; speedup 1.0000x reference)
//
#include <hip/hip_runtime.h>
#include <hip/hip_bf16.h>
#include <hip/hip_fp16.h>
#include <math.h>

// Problem constants (fixed by the reference)
#define N      4096          // N_HID == N_TH == N_TP
#define KSTEPS 8
#define NF     16384         // feature length for W3 (nH + nP + 2*maxL)

// ---------------------------------------------------------------------------
// fp32 -> fp16 conversion. One thread = 8 elements (read 32 B, write 16 B).
// n divisible by 8 guaranteed (all matrices are multiples of 4096^2).
// ---------------------------------------------------------------------------
__global__ void cvt_kernel(const float* __restrict__ src,
                           __half* __restrict__ dst) {
    size_t idx = (size_t)blockIdx.x * blockDim.x + threadIdx.x;
    const float4* s4 = (const float4*)src;
    float4 a = s4[2 * idx];
    float4 b = s4[2 * idx + 1];
    union { float4 f; __half2 h[4]; } u;
    u.h[0] = __floats2half2_rn(a.x, a.y);
    u.h[1] = __floats2half2_rn(a.z, a.w);
    u.h[2] = __floats2half2_rn(b.x, b.y);
    u.h[3] = __floats2half2_rn(b.z, b.w);
    ((float4*)dst)[idx] = u.f;
}

// ---------------------------------------------------------------------------
// fp32 weighted column sum (used for the M_h setup path only):
// out[j] += sum_{i in slice} w[i] * M[i][j].  grid=(4,128), block=256.
// out must be pre-zeroed.
// ---------------------------------------------------------------------------
__global__ void colsum_kernel(const float* __restrict__ M,
                              const float* __restrict__ w,
                              float* __restrict__ out,
                              int rowsPerSlice) {
    int c4 = blockIdx.x * blockDim.x + threadIdx.x;      // float4 column idx [0,1024)
    int i0 = blockIdx.y * rowsPerSlice;
    float4 acc = make_float4(0.f, 0.f, 0.f, 0.f);
    for (int i = i0; i < i0 + rowsPerSlice; ++i) {
        float wi = w[i];
        float4 m = ((const float4*)(M + (size_t)i * N))[c4];
        acc.x += wi * m.x;
        acc.y += wi * m.y;
        acc.z += wi * m.z;
        acc.w += wi * m.w;
    }
    atomicAdd(&out[c4 * 4 + 0], acc.x);
    atomicAdd(&out[c4 * 4 + 1], acc.y);
    atomicAdd(&out[c4 * 4 + 2], acc.z);
    atomicAdd(&out[c4 * 4 + 3], acc.w);
}

// ---------------------------------------------------------------------------
// fp16 weighted column sum: out[j] += sum_{i in slice} w[i] * Mh[i][j].
// grid=(2,128), block=256. Thread owns 8 consecutive columns (one float4 of
// halfs per row).  out (fp32) must be pre-zeroed.
// ---------------------------------------------------------------------------
__global__ void colsum_h_kernel(const __half* __restrict__ M,
                                const float* __restrict__ w,
                                float* __restrict__ out,
                                int rowsPerSlice) {
    int c8 = blockIdx.x * blockDim.x + threadIdx.x;      // 8-col group [0,512)
    int i0 = blockIdx.y * rowsPerSlice;
    float acc[8] = {0.f, 0.f, 0.f, 0.f, 0.f, 0.f, 0.f, 0.f};
    for (int i = i0; i < i0 + rowsPerSlice; ++i) {
        float wi = w[i];
        union { float4 f; __half2 h[4]; } u;
        u.f = ((const float4*)(M + (size_t)i * N))[c8];
        float2 p0 = __half22float2(u.h[0]);
        float2 p1 = __half22float2(u.h[1]);
        float2 p2 = __half22float2(u.h[2]);
        float2 p3 = __half22float2(u.h[3]);
        acc[0] += wi * p0.x; acc[1] += wi * p0.y;
        acc[2] += wi * p1.x; acc[3] += wi * p1.y;
        acc[4] += wi * p2.x; acc[5] += wi * p2.y;
        acc[6] += wi * p3.x; acc[7] += wi * p3.y;
    }
    int base = c8 * 8;
    #pragma unroll
    for (int q = 0; q < 8; ++q) atomicAdd(&out[base + q], acc[q]);
}

// ---------------------------------------------------------------------------
// u[row] = dot(W2h[row,:], sk) with fp16 W2.  One block per row.
// Also zeroes bufv[row] for the following atomic colsum.
// ---------------------------------------------------------------------------
__global__ void rowdot_h_kernel(const __half* __restrict__ W2h,
                                const float* __restrict__ sk,
                                float* __restrict__ u,
                                float* __restrict__ bufv) {
    int row = blockIdx.x;
    const float4* r = (const float4*)(W2h + (size_t)row * N);   // 8 halfs each
    const float4* x = (const float4*)sk;
    float acc = 0.f;
    for (int c = threadIdx.x; c < N / 8; c += blockDim.x) {
        union { float4 f; __half2 h[4]; } w;
        w.f = r[c];
        float4 x0 = x[2 * c], x1 = x[2 * c + 1];
        float2 p0 = __half22float2(w.h[0]);
        float2 p1 = __half22float2(w.h[1]);
        float2 p2 = __half22float2(w.h[2]);
        float2 p3 = __half22float2(w.h[3]);
        acc += p0.x * x0.x + p0.y * x0.y + p1.x * x0.z + p1.y * x0.w
             + p2.x * x1.x + p2.y * x1.y + p3.x * x1.z + p3.y * x1.w;
    }
    __shared__ float red[256];
    red[threadIdx.x] = acc;
    __syncthreads();
    for (int s = 128; s > 0; s >>= 1) {
        if (threadIdx.x < s) red[threadIdx.x] += red[threadIdx.x + s];
        __syncthreads();
    }
    if (threadIdx.x == 0) {
        u[row]    = red[0];
        bufv[row] = 0.f;
    }
}

// ---------------------------------------------------------------------------
// Single-block softmax over N entries: wgt = softmax(v).
// Optionally zeroes zbuf[0..N) (the xk accumulator for the next colsum).
// ---------------------------------------------------------------------------
__global__ void softmax_kernel(const float* __restrict__ v,
                               float* __restrict__ wgt,
                               float* __restrict__ zbuf) {
    __shared__ float red[1024];
    int tid = threadIdx.x;
    float m = -1e30f;
    for (int i = tid; i < N; i += 1024) m = fmaxf(m, v[i]);
    red[tid] = m;
    __syncthreads();
    for (int s = 512; s > 0; s >>= 1) {
        if (tid < s) red[tid] = fmaxf(red[tid], red[tid + s]);
        __syncthreads();
    }
    float mx = red[0];
    __syncthreads();
    float sum = 0.f;
    for (int i = tid; i < N; i += 1024) {
        float e = expf(v[i] - mx);
        wgt[i] = e;
        sum += e;
    }
    red[tid] = sum;
    __syncthreads();
    for (int s = 512; s > 0; s >>= 1) {
        if (tid < s) red[tid] += red[tid + s];
        __syncthreads();
    }
    float inv = 1.f / red[0];
    for (int i = tid; i < N; i += 1024) wgt[i] *= inv;
    if (zbuf) {
        for (int i = tid; i < N; i += 1024) zbuf[i] = 0.f;
    }
}

// ---------------------------------------------------------------------------
// Fused GRU cell (fp16 weights): one block per hidden unit t.
// ---------------------------------------------------------------------------
__global__ void gru_h_kernel(const __half* __restrict__ w_ih,
                             const __half* __restrict__ w_hh,
                             const float* __restrict__ xk,
                             const float* __restrict__ h,
                             float* __restrict__ h_out) {
    int t = blockIdx.x;
    float acc[6] = {0.f, 0.f, 0.f, 0.f, 0.f, 0.f};
    const float4* xv = (const float4*)xk;
    const float4* hv = (const float4*)h;
    for (int g = 0; g < 3; ++g) {
        const float4* wi = (const float4*)(w_ih + (size_t)(g * N + t) * N);
        const float4* wh = (const float4*)(w_hh + (size_t)(g * N + t) * N);
        for (int c = threadIdx.x; c < N / 8; c += blockDim.x) {
            union { float4 f; __half2 h2[4]; } a, b;
            a.f = wi[c];
            b.f = wh[c];
            float4 x0 = xv[2 * c], x1 = xv[2 * c + 1];
            float4 h0 = hv[2 * c], h1 = hv[2 * c + 1];
            float2 a0 = __half22float2(a.h2[0]), a1 = __half22float2(a.h2[1]);
            float2 a2 = __half22float2(a.h2[2]), a3 = __half22float2(a.h2[3]);
            float2 b0 = __half22float2(b.h2[0]), b1 = __half22float2(b.h2[1]);
            float2 b2 = __half22float2(b.h2[2]), b3 = __half22float2(b.h2[3]);
            acc[g]     += a0.x * x0.x + a0.y * x0.y + a1.x * x0.z + a1.y * x0.w
                        + a2.x * x1.x + a2.y * x1.y + a3.x * x1.z + a3.y * x1.w;
            acc[3 + g] += b0.x * h0.x + b0.y * h0.y + b1.x * h0.z + b1.y * h0.w
                        + b2.x * h1.x + b2.y * h1.y + b3.x * h1.z + b3.y * h1.w;
        }
    }
    __shared__ float red[6][256];
    for (int g = 0; g < 6; ++g) red[g][threadIdx.x] = acc[g];
    __syncthreads();
    for (int s = 128; s > 0; s >>= 1) {
        if (threadIdx.x < s)
            for (int g = 0; g < 6; ++g)
                red[g][threadIdx.x] += red[g][threadIdx.x + s];
        __syncthreads();
    }
    if (threadIdx.x == 0) {
        float ir = red[0][0], iz = red[1][0], in_ = red[2][0];
        float hr = red[3][0], hz = red[4][0], hn = red[5][0];
        float r = 1.f / (1.f + expf(-(ir + hr)));
        float z = 1.f / (1.f + expf(-(iz + hz)));
        float n = tanhf(in_ + r * hn);
        h_out[t] = (1.f - z) * n + z * h[t];
    }
}

// ---------------------------------------------------------------------------
// Fused label head: logits3 = W3^T feat(s,x) computed in ONE block (no
// atomics, no pre-zero), then P_r += softmax(logits3); finalize writes out.
// ---------------------------------------------------------------------------
__global__ void feat3_kernel(const float* __restrict__ W3,
                             const float* __restrict__ s,
                             const float* __restrict__ x,
                             float* __restrict__ Pr,
                             float* __restrict__ out,
                             int finalize) {
    __shared__ float red[3][1024];
    int tid = threadIdx.x;
    float a0 = 0.f, a1 = 0.f, a2 = 0.f;
    for (int f = tid; f < NF; f += 1024) {
        int j = f & (N - 1);
        int seg = f >> 12;
        float sv = s[j], xv = x[j];
        float val;
        if (seg == 0)      val = sv;
        else if (seg == 1) val = xv;
        else if (seg == 2) val = fabsf(sv - xv);
        else               val = sv * xv;
        a0 += val * W3[f * 3 + 0];
        a1 += val * W3[f * 3 + 1];
        a2 += val * W3[f * 3 + 2];
    }
    red[0][tid] = a0; red[1][tid] = a1; red[2][tid] = a2;
    __syncthreads();
    for (int st = 512; st > 0; st >>= 1) {
        if (tid < st) {
            red[0][tid] += red[0][tid + st];
            red[1][tid] += red[1][tid + st];
            red[2][tid] += red[2][tid + st];
        }
        __syncthreads();
    }
    if (tid == 0) {
        float la = red[0][0], lb = red[1][0], lc = red[2][0];
        float m = fmaxf(la, fmaxf(lb, lc));
        float e0 = expf(la - m), e1 = expf(lb - m), e2 = expf(lc - m);
        float ssum = e0 + e1 + e2;
        float p0 = Pr[0] + e0 / ssum;
        float p1 = Pr[1] + e1 / ssum;
        float p2 = Pr[2] + e2 / ssum;
        Pr[0] = p0; Pr[1] = p1; Pr[2] = p2;
        if (finalize) {
            out[0] = p0 / (float)KSTEPS;
            out[1] = p1 / (float)KSTEPS;
            out[2] = p2 / (float)KSTEPS;
        }
    }
}

extern "C" void kernel_launch(void* const* d_in, const int* in_sizes, int n_in,
                              void* d_out, int out_size, void* d_ws, size_t ws_size,
                              hipStream_t stream) {
    const float* M_h  = (const float*)d_in[0];
    const float* M_p  = (const float*)d_in[1];
    const float* w1   = (const float*)d_in[2];
    const float* W2   = (const float*)d_in[3];
    const float* W3   = (const float*)d_in[4];
    const float* w_ih = (const float*)d_in[5];
    const float* w_hh = (const float*)d_in[6];
    float* out = (float*)d_out;

    // ---- workspace layout -------------------------------------------------
    // fp16 copies of the 4 big matrices (256 MiB), then small fp32 scratch.
    char* base = (char*)d_ws;
    const size_t SZ_NN  = (size_t)N * N * sizeof(__half);        // 32 MiB
    const size_t SZ_3NN = (size_t)3 * N * N * sizeof(__half);    // 96 MiB
    __half* W2h  = (__half*)(base);
    __half* M_ph = (__half*)(base + SZ_NN);
    __half* wihh = (__half*)(base + 2 * SZ_NN);
    __half* whhh = (__half*)(base + 2 * SZ_NN + SZ_3NN);
    float*  fs   = (float*)(base + 2 * SZ_NN + 2 * SZ_3NN);      // fp32 scratch
    float* buf_v = fs;            // 4096  logits scratch
    float* buf_w = fs + 4096;     // 4096  softmax weights (alpha / beta)
    float* sk_a  = fs + 8192;     // 4096  hidden state ping
    float* sk_b  = fs + 12288;    // 4096  hidden state pong
    float* xk    = fs + 16384;    // 4096  GRU input vector
    float* u     = fs + 20480;    // 4096  W2 @ sk
    float* Pr    = fs + 24576;    // 3     accumulated probabilities

    // zero the small fp32 scratch (d_ws is poisoned to 0xAA before each call)
    hipMemsetAsync(fs, 0, (size_t)24580 * sizeof(float), stream);

    // ---- setup: fp16 conversion of the streamed matrices -------------------
    cvt_kernel<<<(N / 8) * (N / 256), 256, 0, stream>>>(W2,   W2h);   // 8192 blocks
    cvt_kernel<<<(N / 8) * (N / 256), 256, 0, stream>>>(M_p,  M_ph);
    cvt_kernel<<<3 * (N / 8) * (N / 256), 256, 0, stream>>>(w_ih, wihh);
    cvt_kernel<<<3 * (N / 8) * (N / 256), 256, 0, stream>>>(w_hh, whhh);

    // ---- setup: alpha = softmax(w1^T M_h); sk0 = alpha @ M_h (fp32 exact) --
    dim3 cs32(4, 128);
    colsum_kernel<<<cs32, 256, 0, stream>>>(M_h, w1, buf_v, 32);
    softmax_kernel<<<1, 1024, 0, stream>>>(buf_v, buf_w, nullptr);
    colsum_kernel<<<cs32, 256, 0, stream>>>(M_h, buf_w, sk_a, 32);

    // ---- K iterations ------------------------------------------------------
    dim3 cs16(2, 128);
    float* h  = sk_a;
    float* hn = sk_b;
    for (int k = 0; k < KSTEPS; ++k) {
        // beta-logits = (W2 @ h)^T @ M_p
        rowdot_h_kernel<<<4096, 256, 0, stream>>>(W2h, h, u, buf_v);
        colsum_h_kernel<<<cs16, 256, 0, stream>>>(M_ph, u, buf_v, 32);
        softmax_kernel<<<1, 1024, 0, stream>>>(buf_v, buf_w, xk); // beta; zero xk
        // xk = beta @ M_p
        colsum_h_kernel<<<cs16, 256, 0, stream>>>(M_ph, buf_w, xk, 32);
        // h' = GRUCell(xk, h)
        gru_h_kernel<<<4096, 256, 0, stream>>>(wihh, whhh, xk, h, hn);
        // P_r += softmax(W3^T feat(h', xk)); finalize on last step
        feat3_kernel<<<1, 1024, 0, stream>>>(W3, hn, xk, Pr, out,
                                             k == KSTEPS - 1 ? 1 : 0);
        float* t = h; h = hn; hn = t;
    }
}